// Round 3
// baseline (280.687 us; speedup 1.0000x reference)
//
#include <hip/hip_runtime.h>
#include <math.h>

// CrossAttention B=2, Sq=Sk=2048, H=16, Hkv=4, D=64, fp32 io.
// R3: fixed-shift softmax (no online max/sum => zero cross-lane ops in main
// loop), row-sum l via MFMA-with-ones, exact wave-cooperative fallback for
// degenerate rows (l==0: all visible keys padded), exp2-space masking.

typedef __bf16 bf16x4 __attribute__((ext_vector_type(4)));
typedef __bf16 bf16x8 __attribute__((ext_vector_type(8)));
typedef float floatx4 __attribute__((ext_vector_type(4)));

#define B_ 2
#define SQ 2048
#define SK 2048
#define H_ 16
#define HKV 4
#define D_ 64
#define QT 64
#define KT 64
#define PADLD 72            // bf16 elems per LDS row
#define KVROW 512           // floats per (b,s) slot in kv: 2*HKV*D
#define NEGV (-10000.0f)
#define QSCL 0.18033688f    // 0.125 * log2(e): scores land in exp2 space
#define EBIAS 17.3123405f   // 12 * log2(e): fixed softmax shift
#define PADNEG (-14444.26f) // NEGV*log2e - EBIAS: exp2 -> exactly 0
#define CAUSNEG (-20000.0f) // causal override in exp2 space -> exactly 0

__global__ __launch_bounds__(256, 4)
void attn_kernel(const float* __restrict__ q,
                 const float* __restrict__ kv,
                 const int* __restrict__ mask,
                 float* __restrict__ out)
{
    __shared__ alignas(16) __bf16 Kt[KT][PADLD];     // K tile [key][d]
    __shared__ alignas(16) __bf16 Vt[D_][PADLD];     // V tile transposed [d][key]
    __shared__ alignas(16) __bf16 Pl[4][16][PADLD];  // per-wave P [qrow][key]
    __shared__ float padf[KT];
    __shared__ float wbuf[4][64];                    // fallback scratch (per wave)

    const int tid  = threadIdx.x;
    const int wave = tid >> 6;
    const int lane = tid & 63;
    const int col  = lane & 15;
    const int quad = lane >> 4;

    const int bh = blockIdx.x;
    const int qt = 31 - (int)blockIdx.y;     // LPT: heavy q-tiles first
    const int b   = bh >> 4;
    const int h   = bh & 15;
    const int hkv = h >> 2;
    const int q0  = qt * QT;
    const int qw  = q0 + wave * 16;

    // ---- Q A-fragments, pre-scaled into exp2 space ----
    bf16x8 aq[2];
    {
        const int row = qw + col;
        const float* qp = q + (((size_t)b * SQ + row) * H_ + h) * D_ + quad * 8;
#pragma unroll
        for (int kc = 0; kc < 2; ++kc) {
            const float* p = qp + kc * 32;
#pragma unroll
            for (int j = 0; j < 8; ++j) aq[kc][j] = (__bf16)(p[j] * QSCL);
        }
    }

    // ones B-fragment for the l row-sum MFMA
    bf16x8 vone;
#pragma unroll
    for (int j = 0; j < 8; ++j) vone[j] = (__bf16)1.0f;

    floatx4 o[4];
    floatx4 l_acc = (floatx4){0.f, 0.f, 0.f, 0.f};
#pragma unroll
    for (int dj = 0; dj < 4; ++dj) o[dj] = (floatx4){0.f, 0.f, 0.f, 0.f};

    // staging thread mappings
    const int kkey = tid >> 4;
    const int kd   = (tid & 15) * 4;
    const int vkey = (tid & 15) * 4;
    const int vd   = (tid >> 4) * 4;

    const float* kvb = kv + (size_t)b * SK * KVROW + hkv * D_;  // K base
    const float* vvb = kvb + HKV * D_;                          // V base

    float4 kreg[4], vreg[4];
    int mreg = 0;

    auto prefetch = [&](int kt) {
        const float* kb = kvb + (size_t)kt * KT * KVROW;
#pragma unroll
        for (int i = 0; i < 4; ++i)
            kreg[i] = *(const float4*)(kb + (kkey + 16 * i) * KVROW + kd);
        const float* vb = kb + HKV * D_;
#pragma unroll
        for (int i = 0; i < 4; ++i)
            vreg[i] = *(const float4*)(vb + (vkey + i) * KVROW + vd);
        if (tid < KT) mreg = mask[b * SK + kt * KT + tid];
    };

    auto stage = [&]() {
#pragma unroll
        for (int i = 0; i < 4; ++i) {
            bf16x4 t = { (__bf16)kreg[i].x, (__bf16)kreg[i].y,
                         (__bf16)kreg[i].z, (__bf16)kreg[i].w };
            *(bf16x4*)&Kt[kkey + 16 * i][kd] = t;
        }
        const float* vf = (const float*)vreg;
#pragma unroll
        for (int j = 0; j < 4; ++j) {
            bf16x4 t = { (__bf16)vf[0 * 4 + j], (__bf16)vf[1 * 4 + j],
                         (__bf16)vf[2 * 4 + j], (__bf16)vf[3 * 4 + j] };
            *(bf16x4*)&Vt[vd + j][vkey] = t;
        }
        if (tid < KT) padf[tid] = mreg ? -EBIAS : PADNEG;  // pad + bias fused
    };

    const int nkt = qt + 1;
    prefetch(0);

    for (int kt = 0; kt < nkt; ++kt) {
        stage();
        __syncthreads();
        if (kt + 1 < nkt) prefetch(kt + 1);   // flies during compute

        // ---- QK^T (already in exp2 space) ----
        floatx4 c[4];
#pragma unroll
        for (int kj = 0; kj < 4; ++kj) {
            c[kj] = (floatx4){0.f, 0.f, 0.f, 0.f};
#pragma unroll
            for (int kc = 0; kc < 2; ++kc) {
                bf16x8 bk = *(const bf16x8*)&Kt[kj * 16 + col][kc * 32 + quad * 8];
                c[kj] = __builtin_amdgcn_mfma_f32_16x16x32_bf16(aq[kc], bk, c[kj], 0, 0, 0);
            }
        }
        // ---- masks + exp2 + P store: no cross-lane ops, no rescale ----
        const bool diag = (kt == qt);
        const int rowl = wave * 16 + quad * 4;
#pragma unroll
        for (int kj = 0; kj < 4; ++kj) {
            const float pf = padf[kj * 16 + col];
            const int keyl = kj * 16 + col;
#pragma unroll
            for (int r = 0; r < 4; ++r) {
                float t = c[kj][r] + pf;
                if (diag && keyl > rowl + r) t = CAUSNEG;
                float p = __builtin_amdgcn_exp2f(t);   // 0 for masked
                Pl[wave][quad * 4 + r][kj * 16 + col] = (__bf16)p;
            }
        }
        // ---- P @ [V | ones]: o and l in one pass (wave-private LDS, no barrier) ----
        bf16x8 ap[2];
#pragma unroll
        for (int kc = 0; kc < 2; ++kc)
            ap[kc] = *(const bf16x8*)&Pl[wave][col][kc * 32 + quad * 8];
#pragma unroll
        for (int kc = 0; kc < 2; ++kc)
            l_acc = __builtin_amdgcn_mfma_f32_16x16x32_bf16(ap[kc], vone, l_acc, 0, 0, 0);
#pragma unroll
        for (int dj = 0; dj < 4; ++dj)
#pragma unroll
            for (int kc = 0; kc < 2; ++kc) {
                bf16x8 bv = *(const bf16x8*)&Vt[dj * 16 + col][kc * 32 + quad * 8];
                o[dj] = __builtin_amdgcn_mfma_f32_16x16x32_bf16(ap[kc], bv, o[dj], 0, 0, 0);
            }
        __syncthreads();
    }

    // ---- rare exact fallback: rows with l==0 (all visible keys padded) ----
    unsigned long long bm[4];
#pragma unroll
    for (int r = 0; r < 4; ++r) bm[r] = __ballot(l_acc[r] == 0.f);
    if (bm[0] | bm[1] | bm[2] | bm[3]) {   // wave-uniform, ~never taken
        for (int r = 0; r < 4; ++r) {
            if (!bm[r]) continue;
            for (int qg = 0; qg < 4; ++qg) {
                if (!((bm[r] >> (qg * 16)) & 1ull)) continue;
                const int R = qw + qg * 4 + r;          // degenerate row
                const float* qrow = q + (((size_t)b * SQ + R) * H_ + h) * D_;
                // pass 1: true max over visible scores (+ NEG from tail if any)
                float mymax = -3.4e38f;
                for (int s = lane; s <= R; s += 64) {
                    const float* kp = kvb + (size_t)s * KVROW;
                    float dt = 0.f;
                    for (int d = 0; d < D_; ++d) dt += qrow[d] * kp[d];
                    float sc = dt * 0.125f + (mask[b * SK + s] ? 0.f : NEGV);
                    mymax = fmaxf(mymax, sc);
                }
#pragma unroll
                for (int off = 32; off >= 1; off >>= 1)
                    mymax = fmaxf(mymax, __shfl_xor(mymax, off, 64));
                const float M = (R < SK - 1) ? fmaxf(mymax, NEGV) : mymax;
                // pass 2: weights, l, and o (lane owns d=lane for o)
                float lsum = 0.f, oacc = 0.f;
                for (int s0 = 0; s0 <= R; s0 += 64) {
                    int s = s0 + lane;
                    float w = 0.f;
                    if (s <= R) {
                        const float* kp = kvb + (size_t)s * KVROW;
                        float dt = 0.f;
                        for (int d = 0; d < D_; ++d) dt += qrow[d] * kp[d];
                        float sc = dt * 0.125f + (mask[b * SK + s] ? 0.f : NEGV);
                        w = __expf(sc - M);
                        lsum += w;
                    }
                    wbuf[wave][lane] = w;   // wave-private LDS: in-order, no barrier
                    const int nk = (R - s0 + 1 < 64) ? (R - s0 + 1) : 64;
                    for (int j = 0; j < nk; ++j)
                        oacc += wbuf[wave][j] * vvb[(size_t)(s0 + j) * KVROW + lane];
                }
#pragma unroll
                for (int off = 32; off >= 1; off >>= 1)
                    lsum += __shfl_xor(lsum, off, 64);
                // analytic causal tail (score == NEG exactly)
                const float wn = __expf(NEGV - M);
                float tacc = 0.f;
                if (wn > 0.f && R < SK - 1) {
                    int s = R + 1;
                    for (; s + 3 < SK; s += 4) {
                        tacc += vvb[(size_t)(s + 0) * KVROW + lane];
                        tacc += vvb[(size_t)(s + 1) * KVROW + lane];
                        tacc += vvb[(size_t)(s + 2) * KVROW + lane];
                        tacc += vvb[(size_t)(s + 3) * KVROW + lane];
                    }
                    for (; s < SK; ++s) tacc += vvb[(size_t)s * KVROW + lane];
                }
                const float ltot = lsum + wn * (float)(SK - 1 - R);
                out[(((size_t)b * SQ + R) * H_ + h) * D_ + lane] =
                    (oacc + wn * tacc) / ltot;
            }
        }
    }

    // ---- epilogue: normalize + store (skip fallback-handled rows: l==0) ----
#pragma unroll
    for (int r = 0; r < 4; ++r) {
        const float l = l_acc[r];
        if (l > 0.f) {
            const float inv = 1.0f / l;
            const int row = qw + quad * 4 + r;
            float* op = out + (((size_t)b * SQ + row) * H_ + h) * D_ + col;
#pragma unroll
            for (int dj = 0; dj < 4; ++dj)
                op[dj * 16] = o[dj][r] * inv;
        }
    }
}

extern "C" void kernel_launch(void* const* d_in, const int* in_sizes, int n_in,
                              void* d_out, int out_size, void* d_ws, size_t ws_size,
                              hipStream_t stream) {
    const float* q   = (const float*)d_in[0];
    const float* kv  = (const float*)d_in[1];
    const int* mask  = (const int*)d_in[2];
    float* out       = (float*)d_out;
    dim3 grid(B_ * H_, SQ / QT);
    attn_kernel<<<grid, 256, 0, stream>>>(q, kv, mask, out);
}

// Round 4
// 226.421 us; speedup vs baseline: 1.2397x; 1.2397x over previous
//
#include <hip/hip_runtime.h>
#include <math.h>

// CrossAttention B=2, Sq=Sk=2048, H=16, Hkv=4, D=64, fp32 io.
// R4: fixed-shift exp2 softmax (no cross-lane ops in main loop), l via
// ones-MFMA; raw s_barrier (no vmcnt drain -> prefetch spans barriers);
// exact per-CU load balance permutation; degenerate rows (all visible keys
// padded == R < first_kept[b]) handled exactly in a tiny separate kernel.

typedef __bf16 bf16x4 __attribute__((ext_vector_type(4)));
typedef __bf16 bf16x8 __attribute__((ext_vector_type(8)));
typedef float floatx4 __attribute__((ext_vector_type(4)));

#define B_ 2
#define SQ 2048
#define SK 2048
#define H_ 16
#define HKV 4
#define D_ 64
#define QT 64
#define KT 64
#define PADLD 72            // 144B rows: 16B-aligned, 2-way bank aliasing (free)
#define KVROW 512           // floats per (b,s) slot: 2*HKV*D
#define NEGV (-10000.0f)
#define QSCL 0.18033688f    // 0.125 * log2(e)
#define EBIAS 17.3123405f   // fixed softmax shift (exp2 space)
#define PADNEG (-14444.26f) // NEGV*log2e - EBIAS -> exp2 == 0 exactly
#define CAUSNEG (-20000.0f) // causal mask in exp2 space -> 0

// raw barrier: publish LDS (lgkmcnt 0) but DO NOT drain vmcnt -> prefetch
// global loads stay in flight across the barrier.
#define WAITB() asm volatile("s_waitcnt lgkmcnt(0)\n\ts_barrier" ::: "memory")

__global__ __launch_bounds__(256, 5)
void attn_kernel(const float* __restrict__ q,
                 const float* __restrict__ kv,
                 const int* __restrict__ mask,
                 float* __restrict__ out)
{
    __shared__ alignas(16) __bf16 Kt[KT][PADLD];
    __shared__ alignas(16) __bf16 Vt[D_][PADLD];
    __shared__ alignas(16) __bf16 Pl[4][16][PADLD];
    __shared__ float padf[KT];

    const int tid  = threadIdx.x;
    const int wave = tid >> 6;
    const int lane = tid & 63;
    const int col  = lane & 15;
    const int quad = lane >> 4;

    // balance permutation: blocks id, id+256, id+512, id+768 land on the same
    // CU slot; their tile counts sum to exactly 66 for every slot.
    const int id = (int)blockIdx.x;
    const int bh = id & 31;
    const int y  = id >> 5;
    const int kg = y >> 3, jj = y & 7;
    const int qt = (kg == 0) ? 31 - jj : (kg == 1) ? jj : (kg == 2) ? 23 - jj : 8 + jj;

    const int b   = bh >> 4;
    const int h   = bh & 15;
    const int hkv = h >> 2;
    const int q0  = qt * QT;
    const int qw  = q0 + wave * 16;

    // ---- Q A-fragments, pre-scaled into exp2 space ----
    bf16x8 aq[2];
    {
        const int row = qw + col;
        const float* qp = q + (((size_t)b * SQ + row) * H_ + h) * D_ + quad * 8;
#pragma unroll
        for (int kc = 0; kc < 2; ++kc) {
            const float* p = qp + kc * 32;
#pragma unroll
            for (int j = 0; j < 8; ++j) aq[kc][j] = (__bf16)(p[j] * QSCL);
        }
    }

    bf16x8 vone;
#pragma unroll
    for (int j = 0; j < 8; ++j) vone[j] = (__bf16)1.0f;

    floatx4 o[4];
    floatx4 l_acc = (floatx4){0.f, 0.f, 0.f, 0.f};
#pragma unroll
    for (int dj = 0; dj < 4; ++dj) o[dj] = (floatx4){0.f, 0.f, 0.f, 0.f};

    const int kkey = tid >> 4;
    const int kd   = (tid & 15) * 4;
    const int vkey = (tid & 15) * 4;
    const int vd   = (tid >> 4) * 4;

    const float* kvb = kv + (size_t)b * SK * KVROW + hkv * D_;

    float4 kreg[4], vreg[4];
    int mreg = 0;

    auto prefetch = [&](int kt) {
        const float* kb = kvb + (size_t)kt * KT * KVROW;
#pragma unroll
        for (int i = 0; i < 4; ++i)
            kreg[i] = *(const float4*)(kb + (kkey + 16 * i) * KVROW + kd);
        const float* vb = kb + HKV * D_;
#pragma unroll
        for (int i = 0; i < 4; ++i)
            vreg[i] = *(const float4*)(vb + (vkey + i) * KVROW + vd);
        if (tid < KT) mreg = mask[b * SK + kt * KT + tid];
    };

    auto stage = [&]() {
#pragma unroll
        for (int i = 0; i < 4; ++i) {
            bf16x4 t = { (__bf16)kreg[i].x, (__bf16)kreg[i].y,
                         (__bf16)kreg[i].z, (__bf16)kreg[i].w };
            *(bf16x4*)&Kt[kkey + 16 * i][kd] = t;
        }
        const float* vf = (const float*)vreg;
#pragma unroll
        for (int j = 0; j < 4; ++j) {
            bf16x4 t = { (__bf16)vf[0 * 4 + j], (__bf16)vf[1 * 4 + j],
                         (__bf16)vf[2 * 4 + j], (__bf16)vf[3 * 4 + j] };
            *(bf16x4*)&Vt[vd + j][vkey] = t;
        }
        if (tid < KT) padf[tid] = mreg ? -EBIAS : PADNEG;
    };

    const int nkt = qt + 1;
    prefetch(0);
    stage();

    for (int kt = 0; kt < nkt; ++kt) {
        WAITB();                               // publish stage(kt) to all waves
        if (kt + 1 < nkt) prefetch(kt + 1);    // flies across the next barrier

        // ---- QK^T ----
        floatx4 c[4];
#pragma unroll
        for (int kj = 0; kj < 4; ++kj) {
            c[kj] = (floatx4){0.f, 0.f, 0.f, 0.f};
#pragma unroll
            for (int kc = 0; kc < 2; ++kc) {
                bf16x8 bk = *(const bf16x8*)&Kt[kj * 16 + col][kc * 32 + quad * 8];
                c[kj] = __builtin_amdgcn_mfma_f32_16x16x32_bf16(aq[kc], bk, c[kj], 0, 0, 0);
            }
        }
        // ---- masks + exp2 + P store ----
        const bool diag = (kt == qt);
        const int rowl = wave * 16 + quad * 4;
#pragma unroll
        for (int kj = 0; kj < 4; ++kj) {
            const float pf = padf[kj * 16 + col];
            const int keyl = kj * 16 + col;
#pragma unroll
            for (int r = 0; r < 4; ++r) {
                float t = c[kj][r] + pf;
                if (diag && keyl > rowl + r) t = CAUSNEG;
                float p = __builtin_amdgcn_exp2f(t);
                Pl[wave][quad * 4 + r][kj * 16 + col] = (__bf16)p;
            }
        }
        // ---- P @ [V | ones] (wave-private LDS round-trip) ----
        bf16x8 ap[2];
#pragma unroll
        for (int kc = 0; kc < 2; ++kc)
            ap[kc] = *(const bf16x8*)&Pl[wave][col][kc * 32 + quad * 8];
#pragma unroll
        for (int kc = 0; kc < 2; ++kc)
            l_acc = __builtin_amdgcn_mfma_f32_16x16x32_bf16(ap[kc], vone, l_acc, 0, 0, 0);
#pragma unroll
        for (int dj = 0; dj < 4; ++dj)
#pragma unroll
            for (int kc = 0; kc < 2; ++kc) {
                bf16x8 bv = *(const bf16x8*)&Vt[dj * 16 + col][kc * 32 + quad * 8];
                o[dj] = __builtin_amdgcn_mfma_f32_16x16x32_bf16(ap[kc], bv, o[dj], 0, 0, 0);
            }

        WAITB();                               // all reads of tile kt done
        if (kt + 1 < nkt) stage();             // vmcnt waited here, not at barrier
    }

    // ---- epilogue: normalize + store; l==0 rows handled by fixup kernel ----
#pragma unroll
    for (int r = 0; r < 4; ++r) {
        const float l = l_acc[r];
        if (l > 0.f) {
            const float inv = 1.0f / l;
            const int row = qw + quad * 4 + r;
            float* op = out + (((size_t)b * SQ + row) * H_ + h) * D_ + col;
#pragma unroll
            for (int dj = 0; dj < 4; ++dj)
                op[dj * 16] = o[dj][r] * inv;
        }
    }
}

// Exact handling of degenerate rows: row R is degenerate iff ALL visible keys
// (0..R) are padded, i.e. R < first_kept[b]. True-max softmax over the
// visible (padded) keys + analytic causal tail (score == NEG exactly).
__global__ __launch_bounds__(256)
void fixup_kernel(const float* __restrict__ q,
                  const float* __restrict__ kv,
                  const int* __restrict__ mask,
                  float* __restrict__ out)
{
    __shared__ int s_first;
    __shared__ float wbuf[4][64];

    const int bh = blockIdx.x;
    const int b = bh >> 4, h = bh & 15, hkv = h >> 2;
    const int tid = threadIdx.x;

    if (tid == 0) s_first = SK;
    __syncthreads();
    int local = SK;
    for (int s = tid; s < SK; s += 256)
        if (mask[b * SK + s]) local = min(local, s);
    atomicMin(&s_first, local);
    __syncthreads();
    const int nfirst = s_first;     // rows 0..nfirst-1 are degenerate
    if (nfirst == 0) return;

    const int wave = tid >> 6, lane = tid & 63;
    const float* kvb = kv + (size_t)b * SK * KVROW + hkv * D_;
    const float* vvb = kvb + HKV * D_;

    for (int R = wave; R < nfirst; R += 4) {
        const float* qrow = q + (((size_t)b * SQ + R) * H_ + h) * D_;
        // pass 1: true max over visible scores
        float mymax = -3.4e38f;
        for (int s = lane; s <= R; s += 64) {
            const float* kp = kvb + (size_t)s * KVROW;
            float dt = 0.f;
            for (int d = 0; d < D_; ++d) dt += qrow[d] * kp[d];
            mymax = fmaxf(mymax, dt * 0.125f + NEGV);   // all visible are padded
        }
#pragma unroll
        for (int off = 32; off >= 1; off >>= 1)
            mymax = fmaxf(mymax, __shfl_xor(mymax, off, 64));
        const float M = (R < SK - 1) ? fmaxf(mymax, NEGV) : mymax;
        // pass 2: weights, l, o (lane owns d=lane)
        float lsum = 0.f, oacc = 0.f;
        for (int s0 = 0; s0 <= R; s0 += 64) {
            int s = s0 + lane;
            float w = 0.f;
            if (s <= R) {
                const float* kp = kvb + (size_t)s * KVROW;
                float dt = 0.f;
                for (int d = 0; d < D_; ++d) dt += qrow[d] * kp[d];
                w = __expf(dt * 0.125f + NEGV - M);
                lsum += w;
            }
            wbuf[wave][lane] = w;   // wave-private, in-order
            const int nk = (R - s0 + 1 < 64) ? (R - s0 + 1) : 64;
            for (int j = 0; j < nk; ++j)
                oacc += wbuf[wave][j] * vvb[(size_t)(s0 + j) * KVROW + lane];
        }
#pragma unroll
        for (int off = 32; off >= 1; off >>= 1)
            lsum += __shfl_xor(lsum, off, 64);
        // analytic tail: keys R+1..SK-1 all have score exactly NEG
        const float wn = __expf(NEGV - M);
        float t0 = 0.f, t1 = 0.f, t2 = 0.f, t3 = 0.f,
              t4 = 0.f, t5 = 0.f, t6 = 0.f, t7 = 0.f;
        int s = R + 1;
        for (; s + 7 < SK; s += 8) {
            t0 += vvb[(size_t)(s + 0) * KVROW + lane];
            t1 += vvb[(size_t)(s + 1) * KVROW + lane];
            t2 += vvb[(size_t)(s + 2) * KVROW + lane];
            t3 += vvb[(size_t)(s + 3) * KVROW + lane];
            t4 += vvb[(size_t)(s + 4) * KVROW + lane];
            t5 += vvb[(size_t)(s + 5) * KVROW + lane];
            t6 += vvb[(size_t)(s + 6) * KVROW + lane];
            t7 += vvb[(size_t)(s + 7) * KVROW + lane];
        }
        for (; s < SK; ++s) t0 += vvb[(size_t)s * KVROW + lane];
        const float tacc = ((t0 + t1) + (t2 + t3)) + ((t4 + t5) + (t6 + t7));
        const float ltot = lsum + wn * (float)(SK - 1 - R);
        out[(((size_t)b * SQ + R) * H_ + h) * D_ + lane] = (oacc + wn * tacc) / ltot;
    }
}

extern "C" void kernel_launch(void* const* d_in, const int* in_sizes, int n_in,
                              void* d_out, int out_size, void* d_ws, size_t ws_size,
                              hipStream_t stream) {
    const float* q   = (const float*)d_in[0];
    const float* kv  = (const float*)d_in[1];
    const int* mask  = (const int*)d_in[2];
    float* out       = (float*)d_out;
    fixup_kernel<<<dim3(B_ * H_), 256, 0, stream>>>(q, kv, mask, out);
    attn_kernel<<<dim3(32 * 32), 256, 0, stream>>>(q, kv, mask, out);
}

// Round 5
// 144.155 us; speedup vs baseline: 1.9471x; 1.5707x over previous
//
#include <hip/hip_runtime.h>
#include <math.h>

// CrossAttention B=2, Sq=Sk=2048, H=16, Hkv=4, D=64, fp32 io.
// R5: R2's proven prefetch pipeline + __syncthreads barriers, fixed-shift
// exp2 softmax (no cross-lane ops), l via ones-MFMA, per-CU balance
// permutation (66 tiles/slot), fast block-cooperative fixup kernel for
// degenerate rows (tail = Vtot - prefix instead of serial 2047-load chain).

typedef __bf16 bf16x4 __attribute__((ext_vector_type(4)));
typedef __bf16 bf16x8 __attribute__((ext_vector_type(8)));
typedef float floatx4 __attribute__((ext_vector_type(4)));

#define B_ 2
#define SQ 2048
#define SK 2048
#define H_ 16
#define HKV 4
#define D_ 64
#define QT 64
#define KT 64
#define PADLD 72            // 144B rows: 16B-aligned, 2-way bank aliasing (free)
#define KVROW 512           // floats per (b,s) slot: 2*HKV*D
#define NEGV (-10000.0f)
#define QSCL 0.18033688f    // 0.125 * log2(e)
#define EBIAS 17.3123405f   // fixed softmax shift (exp2 space)
#define PADNEG (-14444.26f) // NEGV*log2e - EBIAS -> exp2 == 0 exactly
#define CAUSNEG (-20000.0f) // causal mask in exp2 space -> 0

__global__ __launch_bounds__(256, 4)
void attn_kernel(const float* __restrict__ q,
                 const float* __restrict__ kv,
                 const int* __restrict__ mask,
                 float* __restrict__ out)
{
    __shared__ alignas(16) __bf16 Kt[KT][PADLD];
    __shared__ alignas(16) __bf16 Vt[D_][PADLD];
    __shared__ alignas(16) __bf16 Pl[4][16][PADLD];
    __shared__ float padf[KT];

    const int tid  = threadIdx.x;
    const int wave = tid >> 6;
    const int lane = tid & 63;
    const int col  = lane & 15;
    const int quad = lane >> 4;

    // balance permutation: for any round-robin CU assignment that groups
    // blocks by y (stride-256 slots or XCD %8), the 4 co-resident qt values
    // per slot sum to exactly 66 tiles: (32-j)+(j+1)+(24-j)+(9+j).
    const int id = (int)blockIdx.x;
    const int bh = id & 31;
    const int y  = id >> 5;
    const int kg = y >> 3, jj = y & 7;
    const int qt = (kg == 0) ? 31 - jj : (kg == 1) ? jj : (kg == 2) ? 23 - jj : 8 + jj;

    const int b   = bh >> 4;
    const int h   = bh & 15;
    const int hkv = h >> 2;
    const int q0  = qt * QT;
    const int qw  = q0 + wave * 16;

    // ---- Q A-fragments, pre-scaled into exp2 space ----
    bf16x8 aq[2];
    {
        const int row = qw + col;
        const float* qp = q + (((size_t)b * SQ + row) * H_ + h) * D_ + quad * 8;
#pragma unroll
        for (int kc = 0; kc < 2; ++kc) {
            const float* p = qp + kc * 32;
#pragma unroll
            for (int j = 0; j < 8; ++j) aq[kc][j] = (__bf16)(p[j] * QSCL);
        }
    }

    bf16x8 vone;
#pragma unroll
    for (int j = 0; j < 8; ++j) vone[j] = (__bf16)1.0f;

    floatx4 o[4];
    floatx4 l_acc = (floatx4){0.f, 0.f, 0.f, 0.f};
#pragma unroll
    for (int dj = 0; dj < 4; ++dj) o[dj] = (floatx4){0.f, 0.f, 0.f, 0.f};

    const int kkey = tid >> 4;
    const int kd   = (tid & 15) * 4;
    const int vkey = (tid & 15) * 4;
    const int vd   = (tid >> 4) * 4;

    const float* kvb = kv + (size_t)b * SK * KVROW + hkv * D_;

    float4 kreg[4], vreg[4];
    int mreg = 0;

    auto prefetch = [&](int kt) {
        const float* kb = kvb + (size_t)kt * KT * KVROW;
#pragma unroll
        for (int i = 0; i < 4; ++i)
            kreg[i] = *(const float4*)(kb + (kkey + 16 * i) * KVROW + kd);
        const float* vb = kb + HKV * D_;
#pragma unroll
        for (int i = 0; i < 4; ++i)
            vreg[i] = *(const float4*)(vb + (vkey + i) * KVROW + vd);
        if (tid < KT) mreg = mask[b * SK + kt * KT + tid];
    };

    auto stage = [&]() {
#pragma unroll
        for (int i = 0; i < 4; ++i) {
            bf16x4 t = { (__bf16)kreg[i].x, (__bf16)kreg[i].y,
                         (__bf16)kreg[i].z, (__bf16)kreg[i].w };
            *(bf16x4*)&Kt[kkey + 16 * i][kd] = t;
        }
        const float* vf = (const float*)vreg;
#pragma unroll
        for (int j = 0; j < 4; ++j) {
            bf16x4 t = { (__bf16)vf[0 * 4 + j], (__bf16)vf[1 * 4 + j],
                         (__bf16)vf[2 * 4 + j], (__bf16)vf[3 * 4 + j] };
            *(bf16x4*)&Vt[vd + j][vkey] = t;
        }
        if (tid < KT) padf[tid] = mreg ? -EBIAS : PADNEG;
    };

    const int nkt = qt + 1;
    prefetch(0);

    for (int kt = 0; kt < nkt; ++kt) {
        stage();
        __syncthreads();
        if (kt + 1 < nkt) prefetch(kt + 1);   // lands during compute

        // ---- QK^T (exp2 space) ----
        floatx4 c[4];
#pragma unroll
        for (int kj = 0; kj < 4; ++kj) {
            c[kj] = (floatx4){0.f, 0.f, 0.f, 0.f};
#pragma unroll
            for (int kc = 0; kc < 2; ++kc) {
                bf16x8 bk = *(const bf16x8*)&Kt[kj * 16 + col][kc * 32 + quad * 8];
                c[kj] = __builtin_amdgcn_mfma_f32_16x16x32_bf16(aq[kc], bk, c[kj], 0, 0, 0);
            }
        }
        // ---- masks + exp2 + P store: no cross-lane ops, no rescale ----
        const bool diag = (kt == qt);
        const int rowl = wave * 16 + quad * 4;
#pragma unroll
        for (int kj = 0; kj < 4; ++kj) {
            const float pf = padf[kj * 16 + col];
            const int keyl = kj * 16 + col;
#pragma unroll
            for (int r = 0; r < 4; ++r) {
                float t = c[kj][r] + pf;
                if (diag && keyl > rowl + r) t = CAUSNEG;
                float p = __builtin_amdgcn_exp2f(t);
                Pl[wave][quad * 4 + r][kj * 16 + col] = (__bf16)p;
            }
        }
        // ---- P @ [V | ones] (wave-private LDS round-trip, no barrier) ----
        bf16x8 ap[2];
#pragma unroll
        for (int kc = 0; kc < 2; ++kc)
            ap[kc] = *(const bf16x8*)&Pl[wave][col][kc * 32 + quad * 8];
#pragma unroll
        for (int kc = 0; kc < 2; ++kc)
            l_acc = __builtin_amdgcn_mfma_f32_16x16x32_bf16(ap[kc], vone, l_acc, 0, 0, 0);
#pragma unroll
        for (int dj = 0; dj < 4; ++dj)
#pragma unroll
            for (int kc = 0; kc < 2; ++kc) {
                bf16x8 bv = *(const bf16x8*)&Vt[dj * 16 + col][kc * 32 + quad * 8];
                o[dj] = __builtin_amdgcn_mfma_f32_16x16x32_bf16(ap[kc], bv, o[dj], 0, 0, 0);
            }
        __syncthreads();
    }

    // ---- epilogue: normalize + store; l==0 rows written by fixup ----
#pragma unroll
    for (int r = 0; r < 4; ++r) {
        const float l = l_acc[r];
        if (l > 0.f) {
            const float inv = 1.0f / l;
            const int row = qw + quad * 4 + r;
            float* op = out + (((size_t)b * SQ + row) * H_ + h) * D_ + col;
#pragma unroll
            for (int dj = 0; dj < 4; ++dj)
                op[dj * 16] = o[dj][r] * inv;
        }
    }
}

// Degenerate rows: R < first_kept[b] (all visible keys padded). Exact
// softmax over visible keys + analytic causal tail via Vtot - prefix(R).
__global__ __launch_bounds__(256)
void fixup_kernel(const float* __restrict__ q,
                  const float* __restrict__ kv,
                  const int* __restrict__ mask,
                  float* __restrict__ out)
{
    __shared__ int s_first;
    __shared__ float part[4][64];
    __shared__ float wbuf[4][64];

    const int bh = blockIdx.x;
    const int b = bh >> 4, h = bh & 15, hkv = h >> 2;
    const int tid = threadIdx.x;
    const int wave = tid >> 6, lane = tid & 63;

    if (tid == 0) s_first = SK;
    __syncthreads();
    int local = SK;
    for (int s = tid; s < SK; s += 256)
        if (mask[b * SK + s]) local = min(local, s);
    atomicMin(&s_first, local);
    __syncthreads();
    const int nfirst = s_first;     // rows 0..nfirst-1 are degenerate
    if (nfirst == 0) return;

    const float* kvb = kv + (size_t)b * SK * KVROW + hkv * D_;
    const float* vvb = kvb + HKV * D_;

    // cooperative total-V sum: wave w sums s in [512w, 512w+512)
    {
        float a0 = 0.f, a1 = 0.f, a2 = 0.f, a3 = 0.f,
              a4 = 0.f, a5 = 0.f, a6 = 0.f, a7 = 0.f;
        const int s0 = wave * 512;
        for (int s = s0; s < s0 + 512; s += 8) {
            a0 += vvb[(size_t)(s + 0) * KVROW + lane];
            a1 += vvb[(size_t)(s + 1) * KVROW + lane];
            a2 += vvb[(size_t)(s + 2) * KVROW + lane];
            a3 += vvb[(size_t)(s + 3) * KVROW + lane];
            a4 += vvb[(size_t)(s + 4) * KVROW + lane];
            a5 += vvb[(size_t)(s + 5) * KVROW + lane];
            a6 += vvb[(size_t)(s + 6) * KVROW + lane];
            a7 += vvb[(size_t)(s + 7) * KVROW + lane];
        }
        part[wave][lane] = ((a0 + a1) + (a2 + a3)) + ((a4 + a5) + (a6 + a7));
    }
    __syncthreads();
    const float vtotal = part[0][lane] + part[1][lane] + part[2][lane] + part[3][lane];

    for (int R = wave; R < nfirst; R += 4) {
        const float* qrow = q + (((size_t)b * SQ + R) * H_ + h) * D_;
        // pass 1: true max over visible scores (all visible are padded)
        float mymax = -3.4e38f;
        for (int s = lane; s <= R; s += 64) {
            const float* kp = kvb + (size_t)s * KVROW;
            float dt = 0.f;
            for (int d = 0; d < D_; ++d) dt += qrow[d] * kp[d];
            mymax = fmaxf(mymax, dt * 0.125f + NEGV);
        }
#pragma unroll
        for (int off = 32; off >= 1; off >>= 1)
            mymax = fmaxf(mymax, __shfl_xor(mymax, off, 64));
        const float M = (R < SK - 1) ? fmaxf(mymax, NEGV) : mymax;
        // pass 2: weights, l, o, and V-prefix (lane owns d=lane)
        float lsum = 0.f, oacc = 0.f, pref = 0.f;
        for (int s0 = 0; s0 <= R; s0 += 64) {
            int s = s0 + lane;
            float w = 0.f;
            if (s <= R) {
                const float* kp = kvb + (size_t)s * KVROW;
                float dt = 0.f;
                for (int d = 0; d < D_; ++d) dt += qrow[d] * kp[d];
                w = __expf(dt * 0.125f + NEGV - M);
                lsum += w;
            }
            wbuf[wave][lane] = w;   // wave-private, in-order
            const int nk = (R - s0 + 1 < 64) ? (R - s0 + 1) : 64;
            for (int j = 0; j < nk; ++j) {
                const float vj = vvb[(size_t)(s0 + j) * KVROW + lane];
                oacc += wbuf[wave][j] * vj;
                pref += vj;
            }
        }
#pragma unroll
        for (int off = 32; off >= 1; off >>= 1)
            lsum += __shfl_xor(lsum, off, 64);
        // analytic tail: keys R+1..SK-1 all have score exactly NEG
        const float wn   = __expf(NEGV - M);
        const float ltot = lsum + wn * (float)(SK - 1 - R);
        out[(((size_t)b * SQ + R) * H_ + h) * D_ + lane] =
            (oacc + wn * (vtotal - pref)) / ltot;
    }
}

extern "C" void kernel_launch(void* const* d_in, const int* in_sizes, int n_in,
                              void* d_out, int out_size, void* d_ws, size_t ws_size,
                              hipStream_t stream) {
    const float* q   = (const float*)d_in[0];
    const float* kv  = (const float*)d_in[1];
    const int* mask  = (const int*)d_in[2];
    float* out       = (float*)d_out;
    attn_kernel<<<dim3(32 * 32), 256, 0, stream>>>(q, kv, mask, out);
    fixup_kernel<<<dim3(B_ * H_), 256, 0, stream>>>(q, kv, mask, out);
}

// Round 6
// 128.903 us; speedup vs baseline: 2.1775x; 1.1183x over previous
//
#include <hip/hip_runtime.h>
#include <math.h>

// CrossAttention B=2, Sq=Sk=2048, H=16, Hkv=4, D=64, fp32 io.
// R6: 32x32x16 MFMA with QT=128 (halves per-row LDS fragment traffic; kernel
// was LDS-throughput-bound at R5). S^T = K*Q^T so P packs as b64 writes and
// reads back as b128. Pad mask via per-wave ballot -> u64 bit test (exact:
// exp(-10000) underflows to 0 in fp32 for non-degenerate rows). l by
// in-register reduction + shfl_xor(32). Fixup fused as blocks 512..543.

typedef __bf16 bf16x4 __attribute__((ext_vector_type(4)));
typedef __bf16 bf16x8 __attribute__((ext_vector_type(8)));
typedef float floatx4 __attribute__((ext_vector_type(4)));
typedef float floatx16 __attribute__((ext_vector_type(16)));

#define B_ 2
#define SQ 2048
#define SK 2048
#define H_ 16
#define HKV 4
#define D_ 64
#define QT 128
#define KT 64
#define PAD 72              // bf16/row: 144B rows, 16B aligned
#define KVROW 512           // floats per (b,s) slot: 2*HKV*D
#define NEGV (-10000.0f)
#define QSCL 0.18033688f    // 0.125 * log2(e)
#define EBIAS 17.3123405f   // fixed softmax shift (exp2 space)

__global__ __launch_bounds__(256, 2)
void attn_kernel(const float* __restrict__ q,
                 const float* __restrict__ kv,
                 const int* __restrict__ mask,
                 float* __restrict__ out)
{
    __shared__ alignas(16) __bf16 Kt[KT][PAD];      // [key][d]
    __shared__ alignas(16) __bf16 Vt[D_][PAD];      // [d][key]
    __shared__ alignas(16) __bf16 Pl[4][32][PAD];   // [wave][qrow][key]
    __shared__ float linv[4][32];
    __shared__ float fpart[4][64];                  // fixup scratch
    __shared__ float fw[4][64];
    __shared__ int s_first;

    const int tid  = threadIdx.x;
    const int wave = tid >> 6;
    const int lane = tid & 63;

    if (blockIdx.x >= 512) {
        // ================= fixup role: degenerate rows R < first_kept =======
        const int bh = (int)blockIdx.x - 512;
        const int b = bh >> 4, h = bh & 15, hkv = h >> 2;
        if (tid == 0) s_first = SK;
        __syncthreads();
        int local = SK;
        for (int s = tid; s < SK; s += 256)
            if (mask[b * SK + s]) local = min(local, s);
        atomicMin(&s_first, local);
        __syncthreads();
        const int nfirst = s_first;
        if (nfirst == 0) return;

        const float* kvb = kv + (size_t)b * SK * KVROW + hkv * D_;
        const float* vvb = kvb + HKV * D_;
        {
            float a0=0,a1=0,a2=0,a3=0,a4=0,a5=0,a6=0,a7=0;
            const int s0 = wave * 512;
            for (int s = s0; s < s0 + 512; s += 8) {
                a0 += vvb[(size_t)(s+0)*KVROW + lane];
                a1 += vvb[(size_t)(s+1)*KVROW + lane];
                a2 += vvb[(size_t)(s+2)*KVROW + lane];
                a3 += vvb[(size_t)(s+3)*KVROW + lane];
                a4 += vvb[(size_t)(s+4)*KVROW + lane];
                a5 += vvb[(size_t)(s+5)*KVROW + lane];
                a6 += vvb[(size_t)(s+6)*KVROW + lane];
                a7 += vvb[(size_t)(s+7)*KVROW + lane];
            }
            fpart[wave][lane] = ((a0+a1)+(a2+a3)) + ((a4+a5)+(a6+a7));
        }
        __syncthreads();
        const float vtotal = fpart[0][lane]+fpart[1][lane]+fpart[2][lane]+fpart[3][lane];

        for (int R = wave; R < nfirst; R += 4) {
            const float* qrow = q + (((size_t)b * SQ + R) * H_ + h) * D_;
            float mymax = -3.4e38f;
            for (int s = lane; s <= R; s += 64) {
                const float* kp = kvb + (size_t)s * KVROW;
                float dt = 0.f;
                for (int d = 0; d < D_; ++d) dt += qrow[d] * kp[d];
                mymax = fmaxf(mymax, dt * 0.125f + NEGV);
            }
#pragma unroll
            for (int off = 32; off >= 1; off >>= 1)
                mymax = fmaxf(mymax, __shfl_xor(mymax, off, 64));
            const float M = (R < SK - 1) ? fmaxf(mymax, NEGV) : mymax;
            float lsum = 0.f, oacc = 0.f, pref = 0.f;
            for (int s0 = 0; s0 <= R; s0 += 64) {
                int s = s0 + lane;
                float w = 0.f;
                if (s <= R) {
                    const float* kp = kvb + (size_t)s * KVROW;
                    float dt = 0.f;
                    for (int d = 0; d < D_; ++d) dt += qrow[d] * kp[d];
                    w = __expf(dt * 0.125f + NEGV - M);
                    lsum += w;
                }
                fw[wave][lane] = w;   // wave-private, in-order
                const int nk = (R - s0 + 1 < 64) ? (R - s0 + 1) : 64;
                for (int j = 0; j < nk; ++j) {
                    const float vj = vvb[(size_t)(s0 + j) * KVROW + lane];
                    oacc += fw[wave][j] * vj;
                    pref += vj;
                }
            }
#pragma unroll
            for (int off = 32; off >= 1; off >>= 1)
                lsum += __shfl_xor(lsum, off, 64);
            const float wn   = __expf(NEGV - M);
            const float ltot = lsum + wn * (float)(SK - 1 - R);
            out[(((size_t)b * SQ + R) * H_ + h) * D_ + lane] =
                (oacc + wn * (vtotal - pref)) / ltot;
        }
        return;
    }

    // ================= main attention role ==================================
    const int half = lane >> 5;
    const int nn   = lane & 31;

    const int id = (int)blockIdx.x;
    const int bh = id & 31;
    const int y  = id >> 5;                 // 0..15
    const int qt = (y < 8) ? 15 - y : y - 8; // slot pairs (15-j, j): 17 tiles
    const int b = bh >> 4, h = bh & 15, hkv = h >> 2;
    const int q0 = qt * QT;
    const int qrow_g = q0 + wave * 32 + nn;  // this lane's q-row (column of S^T)

    // ---- Q as B-fragments (n=qrow, k=d), pre-scaled into exp2 space ----
    bf16x8 bq[4];
    {
        const float* qp = q + (((size_t)b * SQ + qrow_g) * H_ + h) * D_;
#pragma unroll
        for (int ks = 0; ks < 4; ++ks)
#pragma unroll
            for (int j = 0; j < 8; ++j)
                bq[ks][j] = (__bf16)(qp[ks * 16 + half * 8 + j] * QSCL);
    }

    floatx16 o0, o1;
#pragma unroll
    for (int i = 0; i < 16; ++i) { o0[i] = 0.f; o1[i] = 0.f; }
    float lsum = 0.f;

    const int kkey = tid >> 4;          // K staging: rows kkey+16i
    const int kd   = (tid & 15) * 4;
    const int vkey = (tid & 15) * 4;    // V staging: transpose 4x4
    const int vd   = (tid >> 4) * 4;

    const float* kvb = kv + (size_t)b * SK * KVROW + hkv * D_;

    float4 kreg[4], vreg[4];
    int mreg = 0;

    auto prefetch = [&](int kt) {
        const float* kb = kvb + (size_t)kt * KT * KVROW;
#pragma unroll
        for (int i = 0; i < 4; ++i)
            kreg[i] = *(const float4*)(kb + (kkey + 16 * i) * KVROW + kd);
        const float* vb = kb + HKV * D_;
#pragma unroll
        for (int i = 0; i < 4; ++i)
            vreg[i] = *(const float4*)(vb + (vkey + i) * KVROW + vd);
        mreg = mask[b * SK + kt * KT + lane];   // all waves: same 256B line
    };

    auto stage = [&]() {
#pragma unroll
        for (int i = 0; i < 4; ++i) {
            bf16x4 t = { (__bf16)kreg[i].x, (__bf16)kreg[i].y,
                         (__bf16)kreg[i].z, (__bf16)kreg[i].w };
            *(bf16x4*)&Kt[kkey + 16 * i][kd] = t;
        }
        const float* vf = (const float*)vreg;
#pragma unroll
        for (int j = 0; j < 4; ++j) {
            bf16x4 t = { (__bf16)vf[0*4+j], (__bf16)vf[1*4+j],
                         (__bf16)vf[2*4+j], (__bf16)vf[3*4+j] };
            *(bf16x4*)&Vt[vd + j][vkey] = t;
        }
    };

    const int nkt = 2 * (qt + 1);
    prefetch(0);

    for (int kt = 0; kt < nkt; ++kt) {
        stage();
        const unsigned long long kept = __ballot(mreg != 0);  // current tile
        __syncthreads();
        if (kt + 1 < nkt) prefetch(kt + 1);   // lands during compute

        const int k0 = kt * KT;
        // causal structure: only tiles 2qt (waves 0,1) and 2qt+1 touch the diag
        const bool skipw = (kt == 2*qt + 1) && (wave < 2);   // fully masked
        const bool dg    = (kt == 2*qt) ? (wave < 2) : (kt == 2*qt + 1);

        if (!skipw) {
#pragma unroll
            for (int t2 = 0; t2 < 2; ++t2) {
                // ---- S^T = K * Q^T : D[m=key][n=qrow] ----
                floatx16 cst;
#pragma unroll
                for (int i = 0; i < 16; ++i) cst[i] = 0.f;
#pragma unroll
                for (int ks = 0; ks < 4; ++ks) {
                    bf16x8 ak = *(const bf16x8*)&Kt[t2*32 + nn][ks*16 + half*8];
                    cst = __builtin_amdgcn_mfma_f32_32x32x16_bf16(ak, bq[ks], cst, 0, 0, 0);
                }
                // ---- mask + exp2 + packed P store ----
#pragma unroll
                for (int rq = 0; rq < 4; ++rq) {
                    const int mb = t2*32 + rq*8 + half*4;    // local key of r=0
                    const unsigned bits = (unsigned)(kept >> mb);
                    bf16x4 pk;
#pragma unroll
                    for (int r = 0; r < 4; ++r) {
                        float p = __builtin_amdgcn_exp2f(cst[rq*4 + r] - EBIAS);
                        if (!((bits >> r) & 1u)) p = 0.f;           // pad: exact
                        if (dg && (k0 + mb + r > qrow_g)) p = 0.f;  // causal
                        lsum += p;
                        pk[r] = (__bf16)p;
                    }
                    *(bf16x4*)&Pl[wave][nn][mb] = pk;
                }
            }
            // ---- O += P * V : A[m=qrow][k=key], B=V^T[k=key][n=d] ----
            bf16x8 ap[4];
#pragma unroll
            for (int ks = 0; ks < 4; ++ks)
                ap[ks] = *(const bf16x8*)&Pl[wave][nn][ks*16 + half*8];
#pragma unroll
            for (int ks = 0; ks < 4; ++ks) {
                bf16x8 bv0 = *(const bf16x8*)&Vt[nn][ks*16 + half*8];
                o0 = __builtin_amdgcn_mfma_f32_32x32x16_bf16(ap[ks], bv0, o0, 0, 0, 0);
                bf16x8 bv1 = *(const bf16x8*)&Vt[32 + nn][ks*16 + half*8];
                o1 = __builtin_amdgcn_mfma_f32_32x32x16_bf16(ap[ks], bv1, o1, 0, 0, 0);
            }
        }
        __syncthreads();
    }

    // ---- epilogue: l transpose via wave-private LDS, normalize, store ----
    lsum += __shfl_xor(lsum, 32, 64);
    linv[wave][nn] = (lsum > 0.f) ? 1.f / lsum : 0.f;   // both halves same value
#pragma unroll
    for (int rq = 0; rq < 4; ++rq) {
        const int m0 = rq * 8 + half * 4;
        floatx4 li = *(const floatx4*)&linv[wave][m0];
#pragma unroll
        for (int r = 0; r < 4; ++r) {
            if (li[r] != 0.f) {     // l==0 rows are written by fixup role
                const int row = q0 + wave * 32 + m0 + r;
                float* op = out + (((size_t)b * SQ + row) * H_ + h) * D_ + nn;
                op[0]  = o0[rq*4 + r] * li[r];
                op[32] = o1[rq*4 + r] * li[r];
            }
        }
    }
}

extern "C" void kernel_launch(void* const* d_in, const int* in_sizes, int n_in,
                              void* d_out, int out_size, void* d_ws, size_t ws_size,
                              hipStream_t stream) {
    const float* q   = (const float*)d_in[0];
    const float* kv  = (const float*)d_in[1];
    const int* mask  = (const int*)d_in[2];
    float* out       = (float*)d_out;
    attn_kernel<<<dim3(512 + B_ * H_), 256, 0, stream>>>(q, kv, mask, out);
}